// Round 5
// baseline (307.069 us; speedup 1.0000x reference)
//
#include <hip/hip_runtime.h>
#include <hip/hip_bf16.h>
#include <stdint.h>

// ---------------------------------------------------------------------------
// SelfAttention: X[4,2048,256] fp32; Wq/Wk/Wv [256,2048]; Wo [2048,256]; bo[256]
//   cast:  Xb = bf16(X); Wqt/Wkt = bf16(0.25*sqrt(log2e)*W^T); Wvt/Wot = W^T
//   qk = Xb @ [Wqt;Wkt]^T  [8192][4096] bf16 (q cols 0..2047, k cols 2048..)
//   vt = Wvt @ Xb^T        [2048][8192] bf16 (rows = h*256+d)
//   attn2: 8 waves x 32 q-rows, 32x32x16 MFMA, swapped QK^T, in-reg softmax
//          (exp2), HALF-TILE SCORE LOOKAHEAD: QK(H+1) issued before SM(H)/PV(H)
//          so the dependent MFMA chain retires under softmax+PV work.
//   out = ctx @ Wot^T + bo  fp32
// ---------------------------------------------------------------------------

using short8 = __attribute__((ext_vector_type(8))) short;   // 8 bf16 = 4 VGPR
using f32x4  = __attribute__((ext_vector_type(4))) float;
using f32x16 = __attribute__((ext_vector_type(16))) float;

#define MFMA16(a, b, c) __builtin_amdgcn_mfma_f32_16x16x32_bf16((a), (b), (c), 0, 0, 0)
#define MFMA32(a, b, c) __builtin_amdgcn_mfma_f32_32x32x16_bf16((a), (b), (c), 0, 0, 0)

#if __has_builtin(__builtin_amdgcn_exp2f)
#define EXP2(x) __builtin_amdgcn_exp2f(x)
#else
#define EXP2(x) exp2f(x)
#endif

__device__ __forceinline__ uint16_t f2bf(float f) {
  union { float f; uint32_t u; } v; v.f = f;
  uint32_t u = v.u;
  u += 0x7fffu + ((u >> 16) & 1u);     // round-to-nearest-even
  return (uint16_t)(u >> 16);
}

__device__ __forceinline__ uint32_t cvtpk_bf16(float lo, float hi) {
  uint32_t r;
  asm("v_cvt_pk_bf16_f32 %0, %1, %2" : "=v"(r) : "v"(lo), "v"(hi));
  return r;
}

// swap a's hi-32-lane half with b's lo-32-lane half (both operands updated)
__device__ __forceinline__ void swap32(uint32_t& a, uint32_t& b) {
  asm volatile("v_permlane32_swap_b32 %0, %1" : "+v"(a), "+v"(b));
}

// global -> LDS direct (16B per lane; LDS dest = wave-uniform base + lane*16)
__device__ __forceinline__ void gll16(const void* g, void* l) {
  __builtin_amdgcn_global_load_lds(
      (const __attribute__((address_space(1))) void*)g,
      (__attribute__((address_space(3))) void*)l, 16, 0, 0);
}

// ---------------------------------------------------------------------------
__global__ __launch_bounds__(256) void cast_x_k(const float* __restrict__ X,
                                                uint16_t* __restrict__ Xb, int n4) {
  int i = blockIdx.x * 256 + threadIdx.x;
  if (i >= n4) return;
  float4 v = ((const float4*)X)[i];
  union { uint16_t u[4]; uint2 p; } r;
  r.u[0] = f2bf(v.x); r.u[1] = f2bf(v.y); r.u[2] = f2bf(v.z); r.u[3] = f2bf(v.w);
  ((uint2*)Xb)[i] = r.p;
}

// transpose-cast: W[R][C] fp32 -> Wt[C][R] bf16, times scale. grid (C/64, R/64)
__global__ __launch_bounds__(256) void tcast_k(const float* __restrict__ W,
                                               uint16_t* __restrict__ Wt,
                                               int R, int C, float scale) {
  __shared__ float T[64][65];
  int c0 = blockIdx.x * 64, r0 = blockIdx.y * 64;
  int tid = threadIdx.x;
  int cc = tid & 63;
  for (int rr = tid >> 6; rr < 64; rr += 4)
    T[rr][cc] = W[(size_t)(r0 + rr) * C + c0 + cc];
  __syncthreads();
  int n = tid >> 2, kb = (tid & 3) * 16;
  uint16_t* orow = Wt + (size_t)(c0 + n) * R + r0 + kb;
#pragma unroll
  for (int j = 0; j < 16; ++j) orow[j] = f2bf(T[kb + j][n] * scale);
}

// ---------------------------------------------------------------------------
// C[m][n] = sum_k A[m][k] * Bt[n][k]; 128x128 tile, 4 waves, BK=64.
template <int EPI>
__global__ __launch_bounds__(256) void gemm_bt_k(const uint16_t* __restrict__ A,
                                                 const uint16_t* __restrict__ Bt,
                                                 void* __restrict__ Cv,
                                                 const float* __restrict__ bias,
                                                 int M, int N, int K) {
  __shared__ uint16_t As[128 * 64];
  __shared__ uint16_t Bs[128 * 64];
  const int tid = threadIdx.x;
  const int wv = tid >> 6, lane = tid & 63;
  const int ql = lane & 15, gq = lane >> 4;
  const int wr = wv >> 1, wc = wv & 1;
  const int m0 = blockIdx.y * 128, n0 = blockIdx.x * 128;

  f32x4 acc[4][4];
#pragma unroll
  for (int i = 0; i < 4; ++i)
#pragma unroll
    for (int j = 0; j < 4; ++j) acc[i][j] = (f32x4){0.f, 0.f, 0.f, 0.f};

  const int nkb = K >> 6;
  for (int kb = 0; kb < nkb; ++kb) {
#pragma unroll
    for (int j = 0; j < 4; ++j) {
      int s = (wv * 4 + j) * 64 + lane;
      int row = s >> 3, c = s & 7;
      int gc = c ^ (row & 7);
      gll16(A + (size_t)(m0 + row) * K + kb * 64 + gc * 8, &As[(wv * 4 + j) * 512]);
      gll16(Bt + (size_t)(n0 + row) * K + kb * 64 + gc * 8, &Bs[(wv * 4 + j) * 512]);
    }
    __syncthreads();

    short8 af[4][2], bf[4][2];
#pragma unroll
    for (int mt = 0; mt < 4; ++mt)
#pragma unroll
      for (int kk = 0; kk < 2; ++kk) {
        int row = wr * 64 + mt * 16 + ql;
        int c = (kk * 4 + gq) ^ (row & 7);
        af[mt][kk] = *(const short8*)&As[row * 64 + c * 8];
      }
#pragma unroll
    for (int nt = 0; nt < 4; ++nt)
#pragma unroll
      for (int kk = 0; kk < 2; ++kk) {
        int row = wc * 64 + nt * 16 + ql;
        int c = (kk * 4 + gq) ^ (row & 7);
        bf[nt][kk] = *(const short8*)&Bs[row * 64 + c * 8];
      }
#pragma unroll
    for (int kk = 0; kk < 2; ++kk)
#pragma unroll
      for (int mt = 0; mt < 4; ++mt)
#pragma unroll
        for (int nt = 0; nt < 4; ++nt)
          acc[mt][nt] = MFMA16(af[mt][kk], bf[nt][kk], acc[mt][nt]);
    __syncthreads();
  }

#pragma unroll
  for (int mt = 0; mt < 4; ++mt)
#pragma unroll
    for (int nt = 0; nt < 4; ++nt)
#pragma unroll
      for (int r = 0; r < 4; ++r) {
        int m = m0 + wr * 64 + mt * 16 + gq * 4 + r;
        int n = n0 + wc * 64 + nt * 16 + ql;
        float v = acc[mt][nt][r];
        if (EPI == 0) {
          ((uint16_t*)Cv)[(size_t)m * N + n] = f2bf(v);
        } else {
          ((float*)Cv)[(size_t)m * N + n] = v + bias[n];
        }
      }
}

// ---------------------------------------------------------------------------
// attn2: 8 waves x 32 q-rows; 64 half-tiles of 32 keys; score lookahead of 1.
// K(u) in Kbuf[u&1] (staged 2 tiles ahead); V(u) in Vbuf[u&1] (1 tile ahead).
// Per-tile sync at odd-body end drains staging + WAR-guards buffers.
__global__ __launch_bounds__(512, 2) void attn2_k(const uint16_t* __restrict__ qk,
                                                  const uint16_t* __restrict__ vtws,
                                                  uint16_t* __restrict__ ctx,
                                                  int b0, int nb) {
  __shared__ uint16_t Ks[2][64 * 256];   // [key][d], 16B chunk c at c^(key&7)
  __shared__ uint16_t Vts[2][256 * 64];  // [d][key], 16B chunk c at c^(d&7)
  const int S = 2048;
  // XCD-grouped decode: h == blockIdx%8 == XCD -> each XCD's L2 holds 1 head
  const int h = blockIdx.x & 7;
  const int t = blockIdx.x >> 3;
  const int bb = t >> 3, qb = t & 7;
  const int tid = threadIdx.x, w = tid >> 6, lane = tid & 63;
  const int l31 = lane & 31, hi = lane >> 5;
  const size_t SN = (size_t)nb * S;

  // ---- Q fragments (B-operand): Q[q=l31][ds*16 + hi*8 .. +7], 16 d-slots
  short8 qf[16];
  {
    const uint16_t* qrow =
        qk + (size_t)(bb * S + qb * 256 + w * 32 + l31) * 4096 + h * 256 + hi * 8;
#pragma unroll
    for (int ds = 0; ds < 16; ++ds) qf[ds] = *(const short8*)(qrow + ds * 16);
  }

  // ---- per-lane staging byte-offsets (hoisted; step per k-tile is uniform)
  uint32_t ok[4], ov[4];
#pragma unroll
  for (int j = 0; j < 4; ++j) {
    int s = (j * 8 + w) * 64 + lane;
    int krow = s >> 5, kc = s & 31;
    int kgc = kc ^ (krow & 7);
    ok[j] = (uint32_t)(((bb * S + krow) * 4096 + 2048 + h * 256 + kgc * 8) * 2);
    int d = s >> 3, vc = s & 7;
    int vgc = vc ^ (d & 7);
    ov[j] = (uint32_t)((((h * 256 + d) * SN) + (size_t)bb * S + vgc * 8) * 2);
  }
  const uint32_t kstep = 64 * 4096 * 2;  // 64 key-rows (qk row stride 4096)
  const uint32_t vstep = 64 * 2;         // 64 key-cols

  const char* kgbase = (const char*)qk;
  const char* vgbase = (const char*)vtws;

  auto stageK = [&](int u) {             // K(u) -> Kbuf[u&1]
#pragma unroll
    for (int j = 0; j < 4; ++j)
      gll16(kgbase + ok[j] + (uint32_t)u * kstep, &Ks[u & 1][(j * 8 + w) * 512]);
  };
  auto stageV = [&](int u) {             // V(u) -> Vbuf[u&1]
#pragma unroll
    for (int j = 0; j < 4; ++j)
      gll16(vgbase + ov[j] + (uint32_t)u * vstep, &Vts[u & 1][(j * 8 + w) * 512]);
  };

  f32x16 cacc[8];
#pragma unroll
  for (int db = 0; db < 8; ++db)
#pragma unroll
    for (int r = 0; r < 16; ++r) cacc[db][r] = 0.f;
  float m_run = -3e38f, l_run = 0.f;

  const int rx = (l31 & 7) << 4;          // XOR swizzle: (row&7)<<4 bytes
  const int hi16 = hi << 4;

  // QK over one 32-key half H (keys half*32..+31 of tile H>>1) into s
  auto qk_half = [&](f32x16& s, int H) {
    const char* kr =
        (const char*)&Ks[(H >> 1) & 1][0] + ((H & 1) * 32 + l31) * 512;
#pragma unroll
    for (int r = 0; r < 16; ++r) s[r] = 0.f;
    __builtin_amdgcn_s_setprio(1);
#pragma unroll
    for (int ds = 0; ds < 16; ++ds) {
      int off = (ds * 32 + hi16) ^ rx;
      s = MFMA32(*(const short8*)(kr + off), qf[ds], s);
    }
    __builtin_amdgcn_s_setprio(0);
  };

  // softmax (log2 domain) + pack + PV over one 32-key half held in s
  auto sm_pv = [&](f32x16& s, int H) {
    const char* vbase = (const char*)&Vts[(H >> 1) & 1][0];
    const int ksbase = (H & 1) * 2;
    float pm = fmaxf(
        fmaxf(fmaxf(fmaxf(s[0], s[1]), fmaxf(s[2], s[3])),
              fmaxf(fmaxf(s[4], s[5]), fmaxf(s[6], s[7]))),
        fmaxf(fmaxf(fmaxf(s[8], s[9]), fmaxf(s[10], s[11])),
              fmaxf(fmaxf(s[12], s[13]), fmaxf(s[14], s[15]))));
    pm = fmaxf(pm, __shfl_xor(pm, 32));

    if (__any(pm - m_run > 8.0f)) {      // defer-max: rescale only on growth
      float mn = fmaxf(m_run, pm);
      float al = EXP2(m_run - mn);
      m_run = mn;
      l_run *= al;
#pragma unroll
      for (int r = 0; r < 16; ++r) {
        float a = __shfl(al, (r & 3) + 8 * (r >> 2) + 4 * hi);
#pragma unroll
        for (int db = 0; db < 8; ++db) cacc[db][r] *= a;
      }
    }

    float ps = 0.f;
#pragma unroll
    for (int r = 0; r < 16; ++r) { s[r] = EXP2(s[r] - m_run); ps += s[r]; }
    ps += __shfl_xor(ps, 32);
    l_run += ps;

    // pack P -> two PV A-frags: 8 cvt_pk + 4 permlane32_swap
    uint32_t W[4][2];
#pragma unroll
    for (int g = 0; g < 4; ++g) {
      W[g][0] = cvtpk_bf16(s[4 * g], s[4 * g + 1]);
      W[g][1] = cvtpk_bf16(s[4 * g + 2], s[4 * g + 3]);
    }
    swap32(W[0][0], W[1][0]); swap32(W[0][1], W[1][1]);
    swap32(W[2][0], W[3][0]); swap32(W[2][1], W[3][1]);
    union U { uint32_t u[4]; short8 v; };
    U pa0, pa1;
    pa0.u[0] = W[0][0]; pa0.u[1] = W[0][1]; pa0.u[2] = W[1][0]; pa0.u[3] = W[1][1];
    pa1.u[0] = W[2][0]; pa1.u[1] = W[2][1]; pa1.u[2] = W[3][0]; pa1.u[3] = W[3][1];

    // PV: cacc[db] += P * Vt over this half's 32 keys (8 independent chains)
    __builtin_amdgcn_s_setprio(1);
#pragma unroll
    for (int kh = 0; kh < 2; ++kh) {
      int voff = ((ksbase + kh) * 32 + hi16) ^ rx;   // d&7 == l31&7
      short8 pv = kh ? pa1.v : pa0.v;
#pragma unroll
      for (int db = 0; db < 8; ++db) {
        short8 vf = *(const short8*)(vbase + (db * 32 + l31) * 128 + voff);
        cacc[db] = MFMA32(pv, vf, cacc[db]);
      }
    }
    __builtin_amdgcn_s_setprio(0);
  };

  // body(H): stage (odd H) -> QK(H+1) lookahead -> SM/PV(H) -> sync (odd H)
  auto body = [&](int H, f32x16& cur, f32x16& nxt) {
    if (H & 1) {
      int tt = H >> 1;
      if (tt <= 29) stageK(tt + 2);
      if (tt >= 1 && tt <= 30) stageV(tt + 1);
    }
    if (H < 63) qk_half(nxt, H + 1);
    sm_pv(cur, H);
    if ((H & 1) && H < 63) __syncthreads();
  };

  // prologue: stage tiles 0,1 of K and V; compute scores of half 0
  stageK(0); stageK(1); stageV(0); stageV(1);
  __syncthreads();

  f32x16 sEven, sOdd;
  qk_half(sEven, 0);

  for (int tt = 0; tt < 32; ++tt) {
    body(2 * tt, sEven, sOdd);
    body(2 * tt + 1, sOdd, sEven);
  }

  // ---- epilogue: O[q][d] = cacc/l ; q in reg-dim -> broadcast 1/l per row
  float linv = 1.f / l_run;
  uint16_t* crow = ctx + (size_t)((b0 + bb) * S + qb * 256 + w * 32) * 2048 + h * 256;
#pragma unroll
  for (int r = 0; r < 16; ++r) {
    int qr = (r & 3) + 8 * (r >> 2) + 4 * hi;
    float lr = __shfl(linv, qr);
#pragma unroll
    for (int db = 0; db < 8; ++db)
      crow[(size_t)qr * 2048 + db * 32 + l31] = f2bf(cacc[db][r] * lr);
  }
}

// ---------------------------------------------------------------------------
extern "C" void kernel_launch(void* const* d_in, const int* in_sizes, int n_in,
                              void* d_out, int out_size, void* d_ws, size_t ws_size,
                              hipStream_t stream) {
  const float* X  = (const float*)d_in[0];
  const float* Wq = (const float*)d_in[1];
  const float* Wk = (const float*)d_in[2];
  const float* Wv = (const float*)d_in[3];
  const float* Wo = (const float*)d_in[4];
  const float* bo = (const float*)d_in[5];
  float* out = (float*)d_out;

  const int B = 4, S = 2048, Dm = 256, DH = 2048;
  (void)in_sizes; (void)n_in; (void)out_size; (void)ws_size;

  uint16_t* p = (uint16_t*)d_ws;
  uint16_t* Xb  = p; p += (size_t)B * S * Dm;
  uint16_t* Wqt = p; p += (size_t)DH * Dm;   // Wqt,Wkt contiguous => fused B
  uint16_t* Wkt = p; p += (size_t)DH * Dm;
  uint16_t* Wvt = p; p += (size_t)DH * Dm;
  uint16_t* Wot = p; p += (size_t)Dm * DH;
  uint16_t* ctx = p; p += (size_t)B * S * DH;
  uint16_t* qkw = p; p += (size_t)B * S * (2 * DH);  // [8192][4096]
  uint16_t* vtws = p;                                // [2048][8192]

  // sqrt(log2e) folded into q,k scales -> scores in log2 domain
  const float qs = 0.25f * 1.2011224087864498f;

  cast_x_k<<<dim3((B * S * Dm / 4 + 255) / 256), 256, 0, stream>>>(X, Xb, B * S * Dm / 4);
  tcast_k<<<dim3(DH / 64, Dm / 64), 256, 0, stream>>>(Wq, Wqt, Dm, DH, qs);
  tcast_k<<<dim3(DH / 64, Dm / 64), 256, 0, stream>>>(Wk, Wkt, Dm, DH, qs);
  tcast_k<<<dim3(DH / 64, Dm / 64), 256, 0, stream>>>(Wv, Wvt, Dm, DH, 1.0f);
  tcast_k<<<dim3(Dm / 64, DH / 64), 256, 0, stream>>>(Wo, Wot, DH, Dm, 1.0f);

  // fused q|k projection: [8192][4096]
  gemm_bt_k<0><<<dim3((2 * DH) / 128, (B * S) / 128), 256, 0, stream>>>(
      Xb, Wqt, qkw, nullptr, B * S, 2 * DH, Dm);
  // vt = Wvt @ Xb^T : [2048][8192]
  gemm_bt_k<0><<<dim3((B * S) / 128, DH / 128), 256, 0, stream>>>(
      Wvt, Xb, vtws, nullptr, DH, B * S, Dm);
  attn2_k<<<dim3(64 * B), 512, 0, stream>>>(qkw, vtws, ctx, 0, B);
  gemm_bt_k<1><<<dim3(Dm / 128, (B * S) / 128), 256, 0, stream>>>(
      ctx, Wot, out, bo, B * S, Dm, DH);
}

// Round 6
// 302.087 us; speedup vs baseline: 1.0165x; 1.0165x over previous
//
#include <hip/hip_runtime.h>
#include <hip/hip_bf16.h>
#include <stdint.h>

// ---------------------------------------------------------------------------
// SelfAttention: X[4,2048,256] fp32; Wq/Wk/Wv [256,2048]; Wo [2048,256]; bo[256]
//   cast:  Xb = bf16(X); Wqt/Wkt = bf16(0.25*sqrt(log2e)*W^T); Wvt/Wot = W^T
//   qk = Xb @ [Wqt;Wkt]^T  [8192][4096] bf16 (q cols 0..2047, k cols 2048..)
//   vt = Wvt @ Xb^T        [2048][8192] bf16 (rows = h*256+d)
//   attn2: 8 waves x 32 q-rows, 32x32x16 MFMA, swapped QK^T, in-reg softmax
//          (exp2), R4 flow (both-halves QK interleaved -> SM/PV x2), full
//          32-period XOR swizzles: K rows 512B, V re-blocked [d/4][d&3][key]
//          so every LDS b128 read is 2-way (free) instead of 8-way.
//   out = ctx @ Wot^T + bo  fp32
// ---------------------------------------------------------------------------

using short8 = __attribute__((ext_vector_type(8))) short;   // 8 bf16 = 4 VGPR
using f32x4  = __attribute__((ext_vector_type(4))) float;
using f32x16 = __attribute__((ext_vector_type(16))) float;

#define MFMA16(a, b, c) __builtin_amdgcn_mfma_f32_16x16x32_bf16((a), (b), (c), 0, 0, 0)
#define MFMA32(a, b, c) __builtin_amdgcn_mfma_f32_32x32x16_bf16((a), (b), (c), 0, 0, 0)

#if __has_builtin(__builtin_amdgcn_exp2f)
#define EXP2(x) __builtin_amdgcn_exp2f(x)
#else
#define EXP2(x) exp2f(x)
#endif

__device__ __forceinline__ uint16_t f2bf(float f) {
  union { float f; uint32_t u; } v; v.f = f;
  uint32_t u = v.u;
  u += 0x7fffu + ((u >> 16) & 1u);     // round-to-nearest-even
  return (uint16_t)(u >> 16);
}

__device__ __forceinline__ uint32_t cvtpk_bf16(float lo, float hi) {
  uint32_t r;
  asm("v_cvt_pk_bf16_f32 %0, %1, %2" : "=v"(r) : "v"(lo), "v"(hi));
  return r;
}

// swap a's hi-32-lane half with b's lo-32-lane half (both operands updated)
__device__ __forceinline__ void swap32(uint32_t& a, uint32_t& b) {
  asm volatile("v_permlane32_swap_b32 %0, %1" : "+v"(a), "+v"(b));
}

// global -> LDS direct (16B per lane; LDS dest = wave-uniform base + lane*16)
__device__ __forceinline__ void gll16(const void* g, void* l) {
  __builtin_amdgcn_global_load_lds(
      (const __attribute__((address_space(1))) void*)g,
      (__attribute__((address_space(3))) void*)l, 16, 0, 0);
}

// ---------------------------------------------------------------------------
__global__ __launch_bounds__(256) void cast_x_k(const float* __restrict__ X,
                                                uint16_t* __restrict__ Xb, int n4) {
  int i = blockIdx.x * 256 + threadIdx.x;
  if (i >= n4) return;
  float4 v = ((const float4*)X)[i];
  union { uint16_t u[4]; uint2 p; } r;
  r.u[0] = f2bf(v.x); r.u[1] = f2bf(v.y); r.u[2] = f2bf(v.z); r.u[3] = f2bf(v.w);
  ((uint2*)Xb)[i] = r.p;
}

// transpose-cast: W[R][C] fp32 -> Wt[C][R] bf16, times scale. grid (C/64, R/64)
__global__ __launch_bounds__(256) void tcast_k(const float* __restrict__ W,
                                               uint16_t* __restrict__ Wt,
                                               int R, int C, float scale) {
  __shared__ float T[64][65];
  int c0 = blockIdx.x * 64, r0 = blockIdx.y * 64;
  int tid = threadIdx.x;
  int cc = tid & 63;
  for (int rr = tid >> 6; rr < 64; rr += 4)
    T[rr][cc] = W[(size_t)(r0 + rr) * C + c0 + cc];
  __syncthreads();
  int n = tid >> 2, kb = (tid & 3) * 16;
  uint16_t* orow = Wt + (size_t)(c0 + n) * R + r0 + kb;
#pragma unroll
  for (int j = 0; j < 16; ++j) orow[j] = f2bf(T[kb + j][n] * scale);
}

// ---------------------------------------------------------------------------
// C[m][n] = sum_k A[m][k] * Bt[n][k]; 128x128 tile, 4 waves, BK=64.
template <int EPI>
__global__ __launch_bounds__(256) void gemm_bt_k(const uint16_t* __restrict__ A,
                                                 const uint16_t* __restrict__ Bt,
                                                 void* __restrict__ Cv,
                                                 const float* __restrict__ bias,
                                                 int M, int N, int K) {
  __shared__ uint16_t As[128 * 64];
  __shared__ uint16_t Bs[128 * 64];
  const int tid = threadIdx.x;
  const int wv = tid >> 6, lane = tid & 63;
  const int ql = lane & 15, gq = lane >> 4;
  const int wr = wv >> 1, wc = wv & 1;
  const int m0 = blockIdx.y * 128, n0 = blockIdx.x * 128;

  f32x4 acc[4][4];
#pragma unroll
  for (int i = 0; i < 4; ++i)
#pragma unroll
    for (int j = 0; j < 4; ++j) acc[i][j] = (f32x4){0.f, 0.f, 0.f, 0.f};

  const int nkb = K >> 6;
  for (int kb = 0; kb < nkb; ++kb) {
#pragma unroll
    for (int j = 0; j < 4; ++j) {
      int s = (wv * 4 + j) * 64 + lane;
      int row = s >> 3, c = s & 7;
      int gc = c ^ (row & 7);
      gll16(A + (size_t)(m0 + row) * K + kb * 64 + gc * 8, &As[(wv * 4 + j) * 512]);
      gll16(Bt + (size_t)(n0 + row) * K + kb * 64 + gc * 8, &Bs[(wv * 4 + j) * 512]);
    }
    __syncthreads();

    short8 af[4][2], bf[4][2];
#pragma unroll
    for (int mt = 0; mt < 4; ++mt)
#pragma unroll
      for (int kk = 0; kk < 2; ++kk) {
        int row = wr * 64 + mt * 16 + ql;
        int c = (kk * 4 + gq) ^ (row & 7);
        af[mt][kk] = *(const short8*)&As[row * 64 + c * 8];
      }
#pragma unroll
    for (int nt = 0; nt < 4; ++nt)
#pragma unroll
      for (int kk = 0; kk < 2; ++kk) {
        int row = wc * 64 + nt * 16 + ql;
        int c = (kk * 4 + gq) ^ (row & 7);
        bf[nt][kk] = *(const short8*)&Bs[row * 64 + c * 8];
      }
#pragma unroll
    for (int kk = 0; kk < 2; ++kk)
#pragma unroll
      for (int mt = 0; mt < 4; ++mt)
#pragma unroll
        for (int nt = 0; nt < 4; ++nt)
          acc[mt][nt] = MFMA16(af[mt][kk], bf[nt][kk], acc[mt][nt]);
    __syncthreads();
  }

#pragma unroll
  for (int mt = 0; mt < 4; ++mt)
#pragma unroll
    for (int nt = 0; nt < 4; ++nt)
#pragma unroll
      for (int r = 0; r < 4; ++r) {
        int m = m0 + wr * 64 + mt * 16 + gq * 4 + r;
        int n = n0 + wc * 64 + nt * 16 + ql;
        float v = acc[mt][nt][r];
        if (EPI == 0) {
          ((uint16_t*)Cv)[(size_t)m * N + n] = f2bf(v);
        } else {
          ((float*)Cv)[(size_t)m * N + n] = v + bias[n];
        }
      }
}

// ---------------------------------------------------------------------------
// attn2: block = 512 thr (8 waves); wave owns 32 q-rows. KVBLK=64, 32 k-tiles.
// Swapped QK: S^T[key][q] = mfma(Kfrag, Qfrag); lane(q=l31) gets q-col.
// LDS swizzles (full 32-chunk XOR, 2-way = free):
//   K : [64 keys][256 d] rows of 512B; chunk c stored at slot c^(row&31)
//   Vt: re-blocked [64][4 sub-d][64 keys] rows of 512B; global (d,key-chunk)
//       -> row d>>2, chunk cg = (d&3)*8 + key/8, stored at slot cg^(row&31)
__global__ __launch_bounds__(512, 2) void attn2_k(const uint16_t* __restrict__ qk,
                                                  const uint16_t* __restrict__ vtws,
                                                  uint16_t* __restrict__ ctx,
                                                  int b0, int nb) {
  __shared__ uint16_t Ks[2][64 * 256];   // 32KB per buf
  __shared__ uint16_t Vts[2][64 * 256];  // 32KB per buf (re-blocked layout)
  const int S = 2048;
  // XCD-grouped decode: h == blockIdx%8 == XCD -> each XCD's L2 holds 1 head
  const int h = blockIdx.x & 7;
  const int t = blockIdx.x >> 3;
  const int bb = t >> 3, qb = t & 7;
  const int tid = threadIdx.x, w = tid >> 6, lane = tid & 63;
  const int l31 = lane & 31, hi = lane >> 5;
  const size_t SN = (size_t)nb * S;

  // ---- Q fragments (B-operand): Q[q=l31][ds*16 + hi*8 .. +7], 16 d-slots
  short8 qf[16];
  {
    const uint16_t* qrow =
        qk + (size_t)(bb * S + qb * 256 + w * 32 + l31) * 4096 + h * 256 + hi * 8;
#pragma unroll
    for (int ds = 0; ds < 16; ++ds) qf[ds] = *(const short8*)(qrow + ds * 16);
  }

  // ---- per-lane staging byte-offsets (hoisted; step per k-tile is uniform)
  uint32_t ok[4], ov[4];
#pragma unroll
  for (int j = 0; j < 4; ++j) {
    int s = (j * 8 + w) * 64 + lane;    // 16B-chunk index within 32KB tile
    int krw = s >> 5, kc = s & 31;      // K: row (key), slot
    int kgc = kc ^ (krw & 31);          // inverse of read swizzle
    ok[j] = (uint32_t)(((bb * S + krw) * 4096 + 2048 + h * 256 + kgc * 8) * 2);
    int vr = s >> 5, vsl = s & 31;      // V: LDS row (d>>2 group), slot
    int cg = vsl ^ (vr & 31);           // global chunk within row
    int d = vr * 4 + (cg >> 3);         // sub-d
    int keyoff = (cg & 7) * 8;          // key start within tile
    ov[j] = (uint32_t)((((h * 256 + d) * SN) + (size_t)bb * S + keyoff) * 2);
  }
  const uint32_t kstep = 64 * 4096 * 2;  // 64 key-rows (qk row stride 4096)
  const uint32_t vstep = 64 * 2;         // 64 key-cols

  const char* kgbase = (const char*)qk;
  const char* vgbase = (const char*)vtws;

  auto stage = [&](int buf, int kb) {
#pragma unroll
    for (int j = 0; j < 4; ++j) {
      gll16(kgbase + ok[j] + (uint32_t)kb * kstep, &Ks[buf][(j * 8 + w) * 512]);
      gll16(vgbase + ov[j] + (uint32_t)kb * vstep, &Vts[buf][(j * 8 + w) * 512]);
    }
  };

  f32x16 cacc[8];
#pragma unroll
  for (int db = 0; db < 8; ++db)
#pragma unroll
    for (int r = 0; r < 16; ++r) cacc[db][r] = 0.f;
  float m_run = -3e38f, l_run = 0.f;

  stage(0, 0);
  __syncthreads();

  const int kx = l31 << 4;               // K read XOR: row&31 == l31
  const int hi16 = hi << 4;
  const int vrow_lo = l31 >> 2;           // V read lane decomposition
  const int vcol_hi = (l31 & 3) * 8;

  // softmax (log2 domain) + pack + PV over one 32-key half held in s
  auto sm_pv = [&](f32x16& s, int ksbase, const char* vbase) {
    float pm = fmaxf(
        fmaxf(fmaxf(fmaxf(s[0], s[1]), fmaxf(s[2], s[3])),
              fmaxf(fmaxf(s[4], s[5]), fmaxf(s[6], s[7]))),
        fmaxf(fmaxf(fmaxf(s[8], s[9]), fmaxf(s[10], s[11])),
              fmaxf(fmaxf(s[12], s[13]), fmaxf(s[14], s[15]))));
    pm = fmaxf(pm, __shfl_xor(pm, 32));

    if (__any(pm - m_run > 8.0f)) {      // defer-max: rescale only on growth
      float mn = fmaxf(m_run, pm);
      float al = EXP2(m_run - mn);
      m_run = mn;
      l_run *= al;
#pragma unroll
      for (int r = 0; r < 16; ++r) {
        float a = __shfl(al, (r & 3) + 8 * (r >> 2) + 4 * hi);
#pragma unroll
        for (int db = 0; db < 8; ++db) cacc[db][r] *= a;
      }
    }

    float ps = 0.f;
#pragma unroll
    for (int r = 0; r < 16; ++r) { s[r] = EXP2(s[r] - m_run); ps += s[r]; }
    ps += __shfl_xor(ps, 32);
    l_run += ps;

    // pack P -> two PV A-frags: 8 cvt_pk + 4 permlane32_swap
    uint32_t W[4][2];
#pragma unroll
    for (int g = 0; g < 4; ++g) {
      W[g][0] = cvtpk_bf16(s[4 * g], s[4 * g + 1]);
      W[g][1] = cvtpk_bf16(s[4 * g + 2], s[4 * g + 3]);
    }
    swap32(W[0][0], W[1][0]); swap32(W[0][1], W[1][1]);
    swap32(W[2][0], W[3][0]); swap32(W[2][1], W[3][1]);
    union U { uint32_t u[4]; short8 v; };
    U pa0, pa1;
    pa0.u[0] = W[0][0]; pa0.u[1] = W[0][1]; pa0.u[2] = W[1][0]; pa0.u[3] = W[1][1];
    pa1.u[0] = W[2][0]; pa1.u[1] = W[2][1]; pa1.u[2] = W[3][0]; pa1.u[3] = W[3][1];

    // PV: cacc[db] += P * Vt over this half's 32 keys (8 independent chains)
    __builtin_amdgcn_s_setprio(1);
#pragma unroll
    for (int kh = 0; kh < 2; ++kh) {
      const int ks = ksbase + kh;        // 16-key step within tile (0..3)
      short8 pv = kh ? pa1.v : pa0.v;
#pragma unroll
      for (int db = 0; db < 8; ++db) {
        int row = db * 8 + vrow_lo;
        int slot = (vcol_hi + ks * 2 + hi) ^ ((db & 3) * 8 + vrow_lo);
        short8 vf = *(const short8*)(vbase + row * 512 + slot * 16);
        cacc[db] = MFMA32(pv, vf, cacc[db]);
      }
    }
    __builtin_amdgcn_s_setprio(0);
  };

  for (int kb = 0; kb < 32; ++kb) {
    const int cur = kb & 1;
    if (kb < 31) stage(cur ^ 1, kb + 1);  // prefetch stays in flight across body

    const char* kbase = (const char*)Ks[cur];
    const char* vbase = (const char*)Vts[cur];
    const char* kr0 = kbase + l31 * 512;
    const char* kr1 = kbase + (32 + l31) * 512;

    // ---- QK for BOTH halves first (2 interleaved chains); the following
    // softmax VALU then overlaps the tail of these MFMAs / PV MFMAs.
    f32x16 sA, sB;
#pragma unroll
    for (int r = 0; r < 16; ++r) { sA[r] = 0.f; sB[r] = 0.f; }
    __builtin_amdgcn_s_setprio(1);
#pragma unroll
    for (int ds = 0; ds < 16; ++ds) {
      int off = (ds * 32 + hi16) ^ kx;
      short8 kA = *(const short8*)(kr0 + off);
      short8 kB = *(const short8*)(kr1 + off);
      sA = MFMA32(kA, qf[ds], sA);
      sB = MFMA32(kB, qf[ds], sB);
    }
    __builtin_amdgcn_s_setprio(0);

    sm_pv(sA, 0, vbase);   // keys [0,32)
    sm_pv(sB, 2, vbase);   // keys [32,64)

    __syncthreads();   // drains prefetch (vmcnt) + guards buffer swap
  }

  // ---- epilogue: O[q][d] = cacc/l ; q in reg-dim -> broadcast 1/l per row
  float linv = 1.f / l_run;
  uint16_t* crow = ctx + (size_t)((b0 + bb) * S + qb * 256 + w * 32) * 2048 + h * 256;
#pragma unroll
  for (int r = 0; r < 16; ++r) {
    int qr = (r & 3) + 8 * (r >> 2) + 4 * hi;
    float lr = __shfl(linv, qr);
#pragma unroll
    for (int db = 0; db < 8; ++db)
      crow[(size_t)qr * 2048 + db * 32 + l31] = f2bf(cacc[db][r] * lr);
  }
}

// ---------------------------------------------------------------------------
extern "C" void kernel_launch(void* const* d_in, const int* in_sizes, int n_in,
                              void* d_out, int out_size, void* d_ws, size_t ws_size,
                              hipStream_t stream) {
  const float* X  = (const float*)d_in[0];
  const float* Wq = (const float*)d_in[1];
  const float* Wk = (const float*)d_in[2];
  const float* Wv = (const float*)d_in[3];
  const float* Wo = (const float*)d_in[4];
  const float* bo = (const float*)d_in[5];
  float* out = (float*)d_out;

  const int B = 4, S = 2048, Dm = 256, DH = 2048;
  (void)in_sizes; (void)n_in; (void)out_size; (void)ws_size;

  uint16_t* p = (uint16_t*)d_ws;
  uint16_t* Xb  = p; p += (size_t)B * S * Dm;
  uint16_t* Wqt = p; p += (size_t)DH * Dm;   // Wqt,Wkt contiguous => fused B
  uint16_t* Wkt = p; p += (size_t)DH * Dm;
  uint16_t* Wvt = p; p += (size_t)DH * Dm;
  uint16_t* Wot = p; p += (size_t)Dm * DH;
  uint16_t* ctx = p; p += (size_t)B * S * DH;
  uint16_t* qkw = p; p += (size_t)B * S * (2 * DH);  // [8192][4096]
  uint16_t* vtws = p;                                // [2048][8192]

  // sqrt(log2e) folded into q,k scales -> scores in log2 domain
  const float qs = 0.25f * 1.2011224087864498f;

  cast_x_k<<<dim3((B * S * Dm / 4 + 255) / 256), 256, 0, stream>>>(X, Xb, B * S * Dm / 4);
  tcast_k<<<dim3(DH / 64, Dm / 64), 256, 0, stream>>>(Wq, Wqt, Dm, DH, qs);
  tcast_k<<<dim3(DH / 64, Dm / 64), 256, 0, stream>>>(Wk, Wkt, Dm, DH, qs);
  tcast_k<<<dim3(DH / 64, Dm / 64), 256, 0, stream>>>(Wv, Wvt, Dm, DH, 1.0f);
  tcast_k<<<dim3(Dm / 64, DH / 64), 256, 0, stream>>>(Wo, Wot, DH, Dm, 1.0f);

  // fused q|k projection: [8192][4096]
  gemm_bt_k<0><<<dim3((2 * DH) / 128, (B * S) / 128), 256, 0, stream>>>(
      Xb, Wqt, qkw, nullptr, B * S, 2 * DH, Dm);
  // vt = Wvt @ Xb^T : [2048][8192]
  gemm_bt_k<0><<<dim3((B * S) / 128, DH / 128), 256, 0, stream>>>(
      Wvt, Xb, vtws, nullptr, DH, B * S, Dm);
  attn2_k<<<dim3(64 * B), 512, 0, stream>>>(qkw, vtws, ctx, 0, B);
  gemm_bt_k<1><<<dim3(Dm / 128, (B * S) / 128), 256, 0, stream>>>(
      ctx, Wot, out, bo, B * S, Dm, DH);
}